// Round 2
// baseline (44424.792 us; speedup 1.0000x reference)
//
#include <hip/hip_runtime.h>
#include <hip/hip_bf16.h>

#define TSTEPS 127
#define NBLK 256
#define NVB 250      // 32000/128
#define MROWS 8128   // 127*64

typedef __hip_bfloat16 bf16;
typedef unsigned short u16;
typedef __attribute__((ext_vector_type(8))) short bf16x8;
typedef __attribute__((ext_vector_type(4))) float f32x4;
typedef __attribute__((ext_vector_type(8))) unsigned short u16x8;

__device__ __forceinline__ float us2f(u16 u){ union{float f;unsigned i;}v; v.i=(unsigned)u<<16; return v.f; }
__device__ __forceinline__ u16 f2us(float f){ __hip_bfloat16 h=__float2bfloat16(f); return *(u16*)&h; }
__device__ __forceinline__ void split2(float x, u16& hi, u16& lo){
  u16 h = f2us(x); float fh = us2f(h); lo = f2us(x - fh); hi = h;
}

// ---------------- grid barrier (persistent kernel) ----------------
__device__ __forceinline__ void gbar(unsigned* cnt, int id){
  __threadfence();
  __syncthreads();
  if (threadIdx.x == 0){
    __hip_atomic_fetch_add(&cnt[id], 1u, __ATOMIC_RELEASE, __HIP_MEMORY_SCOPE_AGENT);
    while (__hip_atomic_load(&cnt[id], __ATOMIC_ACQUIRE, __HIP_MEMORY_SCOPE_AGENT) < (unsigned)NBLK)
      __builtin_amdgcn_s_sleep(2);
  }
  __syncthreads();
  __threadfence();
}

// ---------------- prep kernels ----------------
__global__ void p_wcat(const float* __restrict__ Watt, const float* __restrict__ Wu,
                       float* __restrict__ Wcat){
  int idx = blockIdx.x*256 + threadIdx.x;      // 2048*2048
  int n = idx >> 11, k = idx & 2047;
  Wcat[idx] = (n < 1024) ? Watt[idx] : Wu[(size_t)(n-1024)*3072 + k];
}

__global__ void p_wg(const float* __restrict__ Wih, const float* __restrict__ Whh,
                     u16* __restrict__ Wgh, u16* __restrict__ Wgl){
  int k = blockIdx.x*256 + threadIdx.x;        // 2560
  int j = blockIdx.y;                          // 4096
  float v = (k < 1536) ? Wih[(size_t)j*1536 + k] : Whh[(size_t)j*1024 + (k-1536)];
  u16 hi, lo; split2(v, hi, lo);
  Wgh[(size_t)j*2560 + k] = hi; Wgl[(size_t)j*2560 + k] = lo;
}

__global__ void p_wuh(const float* __restrict__ Wu, u16* __restrict__ Wh, u16* __restrict__ Wl){
  int k = blockIdx.x*256 + threadIdx.x;        // 1024
  int j = blockIdx.y;                          // 1024
  float v = Wu[(size_t)j*3072 + 2048 + k];
  u16 hi, lo; split2(v, hi, lo);
  Wh[(size_t)j*1024 + k] = hi; Wl[(size_t)j*1024 + k] = lo;
}

__global__ void p_y(const int* __restrict__ ids, const float* __restrict__ Etgt,
                    u16* __restrict__ Yh, u16* __restrict__ Yl){
  int e0 = blockIdx.x*256 + threadIdx.x;       // 512
  int row = blockIdx.y;                        // 8128
  int id = ids[row];
  float v = Etgt[(size_t)id*512 + e0];
  u16 hi, lo; split2(v, hi, lo);
  Yh[(size_t)row*512 + e0] = hi; Yl[(size_t)row*512 + e0] = lo;
}

__global__ void p_wv(const float* __restrict__ Wv, u16* __restrict__ Wvb){
  size_t idx = (size_t)blockIdx.x*256 + threadIdx.x;  // 32000*1024
  Wvb[idx] = f2us(Wv[idx]);
}

__global__ void p_init(const float* __restrict__ h0, const float* __restrict__ c0,
                       float* __restrict__ h, float* __restrict__ c,
                       u16* __restrict__ hhi, u16* __restrict__ hlo,
                       u16* __restrict__ ohi, u16* __restrict__ olo,
                       unsigned* __restrict__ cnt){
  int idx = blockIdx.x*256 + threadIdx.x;
  if (idx < 65536){
    float hv = h0[idx]; h[idx] = hv;
    u16 a, b; split2(hv, a, b); hhi[idx] = a; hlo[idx] = b;
    c[idx] = c0[idx];
    ohi[idx] = 0; olo[idx] = 0;
  } else if (idx < 66560){
    cnt[idx - 65536] = 0;
  }
}

// ---------------- prep GEMM (fp32 in): enc_proj + Vu, M=16384 N=2048 K=2048 ----------------
union SharedU {
  struct { u16 a[128*72]; u16 b[128*72]; } st;
  float cc[128*128];
};

__global__ __launch_bounds__(256) void k_gemm32(
    const float* __restrict__ A, const float* __restrict__ Bm,
    const float* __restrict__ bias, u16* __restrict__ ep, u16* __restrict__ vu)
{
  __shared__ SharedU sm;
  const int tid = threadIdx.x;
  const int lane = tid & 63, w = tid >> 6;
  const int wm = w >> 1, wn = w & 1;
  const int n0 = blockIdx.x * 128, m0 = blockIdx.y * 128;
  f32x4 acc[4][4];
#pragma unroll
  for (int i=0;i<4;i++)
#pragma unroll
    for (int j=0;j<4;j++) acc[i][j] = (f32x4)(0.f);

  for (int k0 = 0; k0 < 2048; k0 += 64) {
    __syncthreads();
#pragma unroll
    for (int i=0;i<8;i++){
      int idx = tid + i*256;
      int r = idx >> 4, c4 = idx & 15;
      float4 va = *(const float4*)(&A[(size_t)(m0+r)*2048 + k0 + c4*4]);
      ushort4 sa; sa.x=f2us(va.x); sa.y=f2us(va.y); sa.z=f2us(va.z); sa.w=f2us(va.w);
      *(ushort4*)(&sm.st.a[r*72 + c4*4]) = sa;
      float4 vb = *(const float4*)(&Bm[(size_t)(n0+r)*2048 + k0 + c4*4]);
      ushort4 sb; sb.x=f2us(vb.x); sb.y=f2us(vb.y); sb.z=f2us(vb.z); sb.w=f2us(vb.w);
      *(ushort4*)(&sm.st.b[r*72 + c4*4]) = sb;
    }
    __syncthreads();
#pragma unroll
    for (int kk = 0; kk < 64; kk += 32) {
      bf16x8 af[4], bfr[4];
      int krow = kk + ((lane >> 4) << 3);
#pragma unroll
      for (int m4=0;m4<4;m4++)
        af[m4] = *(const bf16x8*)(&sm.st.a[(wm*64 + m4*16 + (lane & 15))*72 + krow]);
#pragma unroll
      for (int n4=0;n4<4;n4++)
        bfr[n4] = *(const bf16x8*)(&sm.st.b[(wn*64 + n4*16 + (lane & 15))*72 + krow]);
#pragma unroll
      for (int m4=0;m4<4;m4++)
#pragma unroll
        for (int n4=0;n4<4;n4++)
          acc[m4][n4] = __builtin_amdgcn_mfma_f32_16x16x32_bf16(af[m4], bfr[n4], acc[m4][n4], 0,0,0);
    }
  }
  __syncthreads();
#pragma unroll
  for (int m4=0;m4<4;m4++)
#pragma unroll
    for (int n4=0;n4<4;n4++)
#pragma unroll
      for (int i=0;i<4;i++){
        int row = wm*64 + m4*16 + ((lane>>4)<<2) + i;
        int col = wn*64 + n4*16 + (lane&15);
        sm.cc[row*128 + col] = acc[m4][n4][i];
      }
  __syncthreads();
  for (int idx = tid; idx < 128*128; idx += 256) {
    int row = idx >> 7, col = idx & 127;
    int gm = m0 + row, gn = n0 + col;
    float vv = sm.cc[idx];
    if (gn < 1024) { vv += bias[gn]; ep[(size_t)gm*1024 + gn] = f2us(vv); }
    else           { vu[(size_t)gm*1024 + (gn-1024)] = f2us(vv); }
  }
}

// ---------------- persistent recurrence kernel ----------------
__global__ __launch_bounds__(256) void k_loop(
    const u16* __restrict__ Wgh, const u16* __restrict__ Wgl,
    const u16* __restrict__ Wuhh, const u16* __restrict__ Wuhl,
    const u16* __restrict__ Yh, const u16* __restrict__ Yl,
    const u16* __restrict__ ep, const u16* __restrict__ vuu,
    float* __restrict__ h, float* __restrict__ c,
    u16* __restrict__ hhi, u16* __restrict__ hlo,
    u16* __restrict__ ohi, u16* __restrict__ olo,
    float* __restrict__ ebuf, float* __restrict__ pa4,
    float* __restrict__ phB, float* __restrict__ gpart,
    u16* __restrict__ comb, unsigned* __restrict__ cnt)
{
  __shared__ u16 tAh[64*40], tAl[64*40], tBh[64*40], tBl[64*40];
  __shared__ float hl2[16][68];
  __shared__ float al[256];
  __shared__ float red[8];

  const int tid = threadIdx.x, blk = blockIdx.x;
  const int lane = tid & 63, w = tid >> 6;
  int bar = 0;

  for (int t = 0; t < TSTEPS; ++t) {
    // ---- Phase A1: gates partial GEMM (split-bf16 MFMA), K-split 4 ----
    {
      const int bn = blk & 63, ks = blk >> 6;
      const int j0 = bn*64;
      f32x4 acc[4];
#pragma unroll
      for (int i=0;i<4;i++) acc[i] = (f32x4)(0.f);
      const int r = tid >> 2, c8 = (tid & 3)*8;
      const int kbeg = ks*640;
      for (int kt = 0; kt < 20; ++kt) {
        const int k0 = kbeg + kt*32;
        const int kg = k0 + c8;
        u16x8 ah, av, bh, bv;
        if (kg < 1024){
          ah = *(const u16x8*)(ohi + r*1024 + kg);
          av = *(const u16x8*)(olo + r*1024 + kg);
        } else if (kg < 1536){
          size_t o = (size_t)(t*64 + r)*512 + (kg - 1024);
          ah = *(const u16x8*)(Yh + o);
          av = *(const u16x8*)(Yl + o);
        } else {
          ah = *(const u16x8*)(hhi + r*1024 + (kg - 1536));
          av = *(const u16x8*)(hlo + r*1024 + (kg - 1536));
        }
        {
          size_t ob = (size_t)(j0 + r)*2560 + kg;
          bh = *(const u16x8*)(Wgh + ob);
          bv = *(const u16x8*)(Wgl + ob);
        }
        __syncthreads();
        *(u16x8*)&tAh[r*40 + c8] = ah;
        *(u16x8*)&tAl[r*40 + c8] = av;
        *(u16x8*)&tBh[r*40 + c8] = bh;
        *(u16x8*)&tBl[r*40 + c8] = bv;
        __syncthreads();
        const int kof = (lane >> 4)*8;
        bf16x8 bhf = *(const bf16x8*)&tBh[(w*16 + (lane&15))*40 + kof];
        bf16x8 blf = *(const bf16x8*)&tBl[(w*16 + (lane&15))*40 + kof];
#pragma unroll
        for (int m=0;m<4;m++){
          bf16x8 ahf = *(const bf16x8*)&tAh[(m*16 + (lane&15))*40 + kof];
          bf16x8 alf = *(const bf16x8*)&tAl[(m*16 + (lane&15))*40 + kof];
          acc[m] = __builtin_amdgcn_mfma_f32_16x16x32_bf16(ahf, bhf, acc[m], 0,0,0);
          acc[m] = __builtin_amdgcn_mfma_f32_16x16x32_bf16(ahf, blf, acc[m], 0,0,0);
          acc[m] = __builtin_amdgcn_mfma_f32_16x16x32_bf16(alf, bhf, acc[m], 0,0,0);
        }
      }
      float* gp = gpart + (size_t)ks*64*4096;
      const int jc = j0 + w*16 + (lane & 15);
#pragma unroll
      for (int m=0;m<4;m++)
#pragma unroll
        for (int i=0;i<4;i++){
          int b = m*16 + ((lane>>4)<<2) + i;
          gp[b*4096 + jc] = acc[m][i];
        }
    }
    gbar(cnt, bar++);

    // ---- Phase A2: LSTM pointwise ----
    {
      const int idx = blk*256 + tid;
      const int b = idx >> 10, kk = idx & 1023;
      float gi=0.f, gf=0.f, gg=0.f, go=0.f;
#pragma unroll
      for (int z=0; z<4; z++){
        const float* gp = gpart + ((size_t)z*64 + b)*4096;
        gi += gp[kk]; gf += gp[kk+1024]; gg += gp[kk+2048]; go += gp[kk+3072];
      }
      gi = 1.f/(1.f+expf(-gi));
      gf = 1.f/(1.f+expf(-gf));
      gg = tanhf(gg);
      go = 1.f/(1.f+expf(-go));
      float cn = gf*c[idx] + gi*gg;
      float hn = go*tanhf(cn);
      c[idx] = cn; h[idx] = hn;
      u16 a, bb; split2(hn, a, bb);
      hhi[idx] = a; hlo[idx] = bb;
    }
    gbar(cnt, bar++);

    // ---- Phase B1: e_t (blocks 64..255) + ph GEMM (blocks 0..63) ----
    if (blk >= 64) {
      const int u = blk - 64;
      const int nrep = (u < 64) ? 2 : 1;
      for (int rep = 0; rep < nrep; ++rep){
        const int uu = (rep == 0) ? u : (192 + u);
        const int b = uu >> 2, st = uu & 3, s0 = st*64;
        __syncthreads();
        for (int i = tid; i < 1024; i += 256) hl2[i & 15][i >> 4] = h[b*1024 + i];
        __syncthreads();
        for (int q = 0; q < 16; ++q){
          const int s = s0 + w*16 + q - ((w*16 + q) & ~63);  // w in 0..3, q in 0..15 -> w*16+q in 0..63
          const int ss = s0 + ((w*16 + q) & 63);
          const u16* row = ep + ((size_t)(b*256 + ss))*1024 + lane*16;
          u16x8 v0 = *(const u16x8*)row;
          u16x8 v1 = *(const u16x8*)(row + 8);
          float acc = 0.f;
#pragma unroll
          for (int j=0;j<8;j++) acc += us2f(v0[j]) * hl2[j][lane];
#pragma unroll
          for (int j=0;j<8;j++) acc += us2f(v1[j]) * hl2[j+8][lane];
#pragma unroll
          for (int off=32; off; off>>=1) acc += __shfl_xor(acc, off);
          if (lane == 0) ebuf[b*256 + ss] = acc;
          (void)s;
        }
      }
    } else {
      // ph: phB[b][j] = sum_k Wuh[j,k] * h[b,k], split-bf16 MFMA; 64 blocks x 16 j
      const int j0p = blk*16;
      f32x4 pacc = (f32x4)(0.f);
      const int r = tid >> 2, c8 = (tid & 3)*8;
      for (int k0 = 0; k0 < 1024; k0 += 32){
        const int kg = k0 + c8;
        u16x8 ah = *(const u16x8*)(hhi + r*1024 + kg);
        u16x8 av = *(const u16x8*)(hlo + r*1024 + kg);
        u16x8 bh = {0,0,0,0,0,0,0,0}, bv = {0,0,0,0,0,0,0,0};
        if (tid < 64){
          size_t ob = (size_t)(j0p + r)*1024 + kg;   // r in 0..15
          bh = *(const u16x8*)(Wuhh + ob);
          bv = *(const u16x8*)(Wuhl + ob);
        }
        __syncthreads();
        *(u16x8*)&tAh[r*40 + c8] = ah;
        *(u16x8*)&tAl[r*40 + c8] = av;
        if (tid < 64){
          *(u16x8*)&tBh[r*40 + c8] = bh;
          *(u16x8*)&tBl[r*40 + c8] = bv;
        }
        __syncthreads();
        const int kof = (lane >> 4)*8;
        bf16x8 bhf = *(const bf16x8*)&tBh[(lane&15)*40 + kof];
        bf16x8 blf = *(const bf16x8*)&tBl[(lane&15)*40 + kof];
        bf16x8 ahf = *(const bf16x8*)&tAh[(w*16 + (lane&15))*40 + kof];
        bf16x8 alf = *(const bf16x8*)&tAl[(w*16 + (lane&15))*40 + kof];
        pacc = __builtin_amdgcn_mfma_f32_16x16x32_bf16(ahf, bhf, pacc, 0,0,0);
        pacc = __builtin_amdgcn_mfma_f32_16x16x32_bf16(ahf, blf, pacc, 0,0,0);
        pacc = __builtin_amdgcn_mfma_f32_16x16x32_bf16(alf, bhf, pacc, 0,0,0);
      }
      const int jcol = j0p + (lane & 15);
#pragma unroll
      for (int i=0;i<4;i++){
        int b = w*16 + ((lane>>4)<<2) + i;
        phB[b*1024 + jcol] = pacc[i];
      }
    }
    gbar(cnt, bar++);

    // ---- Phase B2: softmax + pa partial ----
    {
      const int b = blk >> 2, st = blk & 3, s0 = st*64;
      float x = ebuf[b*256 + tid];
      float m = x;
#pragma unroll
      for (int off=32; off; off>>=1) m = fmaxf(m, __shfl_xor(m, off));
      if (lane == 0) red[w] = m;
      __syncthreads();
      m = fmaxf(fmaxf(red[0],red[1]), fmaxf(red[2],red[3]));
      float pv = expf(x - m);
      float sv = pv;
#pragma unroll
      for (int off=32; off; off>>=1) sv += __shfl_xor(sv, off);
      if (lane == 0) red[4+w] = sv;
      __syncthreads();
      float tot = red[4]+red[5]+red[6]+red[7];
      al[tid] = pv / tot;
      __syncthreads();
      float a0=0.f, a1=0.f, a2=0.f, a3=0.f;
      const u16* vb = vuu + ((size_t)(b*256 + s0))*1024 + tid*4;
      for (int s=0; s<64; s++){
        float aa = al[s0 + s];
        ushort4 v = *(const ushort4*)(vb + (size_t)s*1024);
        a0 += aa*us2f(v.x); a1 += aa*us2f(v.y); a2 += aa*us2f(v.z); a3 += aa*us2f(v.w);
      }
      float4 o4; o4.x=a0; o4.y=a1; o4.z=a2; o4.w=a3;
      *(float4*)(pa4 + ((size_t)(st*64 + b))*1024 + tid*4) = o4;
    }
    gbar(cnt, bar++);

    // ---- Phase B3: o_t = tanh(pa + ph); write o hi/lo + comb ----
    {
      const int idx = blk*256 + tid;
      const int b = idx >> 10, k = idx & 1023;
      float s = pa4[(size_t)(b)*1024 + k]
              + pa4[(size_t)(64 + b)*1024 + k]
              + pa4[(size_t)(128 + b)*1024 + k]
              + pa4[(size_t)(192 + b)*1024 + k]
              + phB[b*1024 + k];
      float o = tanhf(s);
      u16 oh, ol; split2(o, oh, ol);
      ohi[idx] = oh; olo[idx] = ol;
      comb[(size_t)t*65536 + idx] = oh;
    }
    gbar(cnt, bar++);
  }
}

// ---------------- vocab GEMM (bf16 in) + fused softmax partials ----------------
__global__ __launch_bounds__(256) void k_gemm16(
    const u16* __restrict__ A, const u16* __restrict__ Bm,
    const float* __restrict__ bias,
    float* __restrict__ pm, float* __restrict__ ps,
    float* __restrict__ gl, const int* __restrict__ ids)
{
  __shared__ SharedU sm;
  const int tid = threadIdx.x;
  const int lane = tid & 63, w = tid >> 6;
  const int wm = w >> 1, wn = w & 1;
  const int n0 = blockIdx.x * 128, m0 = blockIdx.y * 128;
  f32x4 acc[4][4];
#pragma unroll
  for (int i=0;i<4;i++)
#pragma unroll
    for (int j=0;j<4;j++) acc[i][j] = (f32x4)(0.f);

  for (int k0 = 0; k0 < 1024; k0 += 64) {
    __syncthreads();
#pragma unroll
    for (int i=0;i<8;i++){
      int idx = i*256 + tid;
      int half = idx >> 10, id2 = idx & 1023;
      int r = id2 >> 3, c8 = (id2 & 7)*8;
      if (half == 0){
        int gm = m0 + r;
        u16x8 v = {0,0,0,0,0,0,0,0};
        if (gm < MROWS) v = *(const u16x8*)(A + (size_t)gm*1024 + k0 + c8);
        *(u16x8*)(&sm.st.a[r*72 + c8]) = v;
      } else {
        u16x8 v = *(const u16x8*)(Bm + (size_t)(n0 + r)*1024 + k0 + c8);
        *(u16x8*)(&sm.st.b[r*72 + c8]) = v;
      }
    }
    __syncthreads();
#pragma unroll
    for (int kk = 0; kk < 64; kk += 32) {
      bf16x8 af[4], bfr[4];
      int krow = kk + ((lane >> 4) << 3);
#pragma unroll
      for (int m4=0;m4<4;m4++)
        af[m4] = *(const bf16x8*)(&sm.st.a[(wm*64 + m4*16 + (lane & 15))*72 + krow]);
#pragma unroll
      for (int n4=0;n4<4;n4++)
        bfr[n4] = *(const bf16x8*)(&sm.st.b[(wn*64 + n4*16 + (lane & 15))*72 + krow]);
#pragma unroll
      for (int m4=0;m4<4;m4++)
#pragma unroll
        for (int n4=0;n4<4;n4++)
          acc[m4][n4] = __builtin_amdgcn_mfma_f32_16x16x32_bf16(af[m4], bfr[n4], acc[m4][n4], 0,0,0);
    }
  }
  __syncthreads();
#pragma unroll
  for (int m4=0;m4<4;m4++)
#pragma unroll
    for (int n4=0;n4<4;n4++)
#pragma unroll
      for (int i=0;i<4;i++){
        int row = wm*64 + m4*16 + ((lane>>4)<<2) + i;
        int col = wn*64 + n4*16 + (lane&15);
        sm.cc[row*128 + col] = acc[m4][n4][i];
      }
  __syncthreads();

  if (tid < 128) {
    int row = tid, gm = m0 + row;
    if (gm < MROWS) {
      float mx = -1e30f;
      for (int j=0;j<128;j++){
        int col = (row + j) & 127;
        float x = sm.cc[row*128+col] + bias[n0+col];
        mx = fmaxf(mx, x);
      }
      float sum = 0.f;
      for (int j=0;j<128;j++){
        int col = (row + j) & 127;
        float x = sm.cc[row*128+col] + bias[n0+col];
        sum += expf(x - mx);
      }
      pm[(size_t)gm*NVB + blockIdx.x] = mx;
      ps[(size_t)gm*NVB + blockIdx.x] = sum;
      int g = ids[gm + 64];
      unsigned d = (unsigned)(g - n0);
      if (d < 128u) gl[gm] = sm.cc[row*128 + (int)d] + bias[g];
    }
  }
}

// ---------------- final reduce ----------------
__global__ void k_reduce(const float* __restrict__ pm, const float* __restrict__ ps,
                         const float* __restrict__ gl, const int* __restrict__ ids,
                         float* __restrict__ out)
{
  int b = blockIdx.x, tid = threadIdx.x;
  int lane = tid & 63, w = tid >> 6;
  __shared__ float wacc[4];
  float accum = 0.f;
  for (int t = w; t < TSTEPS; t += 4) {
    int r = t*64 + b;
    const float* pmr = pm + (size_t)r*NVB;
    const float* psr = ps + (size_t)r*NVB;
    float mx = -1e30f;
    for (int p2 = lane; p2 < NVB; p2 += 64) mx = fmaxf(mx, pmr[p2]);
#pragma unroll
    for (int off=32; off; off>>=1) mx = fmaxf(mx, __shfl_xor(mx, off));
    float sm = 0.f;
    for (int p2 = lane; p2 < NVB; p2 += 64) sm += psr[p2] * expf(pmr[p2] - mx);
#pragma unroll
    for (int off=32; off; off>>=1) sm += __shfl_xor(sm, off);
    if (lane == 0) {
      int g = ids[r + 64];
      if (g != 0) accum += gl[r] - (mx + logf(sm));
    }
  }
  if (lane == 0) wacc[w] = accum;
  __syncthreads();
  if (tid == 0) out[b] = wacc[0]+wacc[1]+wacc[2]+wacc[3];
}

// ---------------- host ----------------
extern "C" void kernel_launch(void* const* d_in, const int* in_sizes, int n_in,
                              void* d_out, int out_size, void* d_ws, size_t ws_size,
                              hipStream_t stream)
{
  const int*   ids  = (const int*)d_in[0];
  const float* vc   = (const float*)d_in[1];
  const float* h0   = (const float*)d_in[2];
  const float* c0   = (const float*)d_in[3];
  const float* Etgt = (const float*)d_in[4];
  const float* Watt = (const float*)d_in[5];
  const float* batt = (const float*)d_in[6];
  const float* Wih  = (const float*)d_in[7];
  const float* Whh  = (const float*)d_in[8];
  const float* Wu   = (const float*)d_in[9];
  const float* Wv   = (const float*)d_in[10];
  const float* bv   = (const float*)d_in[11];
  float* out = (float*)d_out;

  char* p = (char*)d_ws;
  auto alloc = [&](size_t bytes)->char* {
    char* r = p; p += (bytes + 255) & ~(size_t)255; return r;
  };
  unsigned* cnt = (unsigned*)alloc(4096);
  u16* Yh   = (u16*)alloc((size_t)MROWS*512*2);
  u16* Yl   = (u16*)alloc((size_t)MROWS*512*2);
  u16* Wgh  = (u16*)alloc((size_t)4096*2560*2);
  u16* Wgl  = (u16*)alloc((size_t)4096*2560*2);
  u16* Wuhh = (u16*)alloc((size_t)1024*1024*2);
  u16* Wuhl = (u16*)alloc((size_t)1024*1024*2);
  float* Wcat = (float*)alloc((size_t)2048*2048*4);
  u16* ep   = (u16*)alloc((size_t)64*256*1024*2);
  u16* vuu  = (u16*)alloc((size_t)64*256*1024*2);
  u16* Wvb  = (u16*)alloc((size_t)32000*1024*2);
  u16* comb = (u16*)alloc((size_t)8192*1024*2);
  float* h    = (float*)alloc(65536*4);
  float* c    = (float*)alloc(65536*4);
  u16* hhi  = (u16*)alloc(65536*2);
  u16* hlo  = (u16*)alloc(65536*2);
  u16* ohi  = (u16*)alloc(65536*2);
  u16* olo  = (u16*)alloc(65536*2);
  float* ebuf = (float*)alloc((size_t)64*256*4);
  float* pa4  = (float*)alloc((size_t)4*64*1024*4);
  float* phB  = (float*)alloc((size_t)64*1024*4);
  float* gpart= (float*)alloc((size_t)4*64*4096*4);
  float* pm   = (float*)alloc((size_t)MROWS*NVB*4);
  float* ps   = (float*)alloc((size_t)MROWS*NVB*4);
  float* gl   = (float*)alloc((size_t)MROWS*4);

  p_init<<<260, 256, 0, stream>>>(h0, c0, h, c, hhi, hlo, ohi, olo, cnt);
  p_wcat<<<(2048*2048)/256, 256, 0, stream>>>(Watt, Wu, Wcat);
  p_wg<<<dim3(10, 4096), 256, 0, stream>>>(Wih, Whh, Wgh, Wgl);
  p_wuh<<<dim3(4, 1024), 256, 0, stream>>>(Wu, Wuhh, Wuhl);
  p_y<<<dim3(2, MROWS), 256, 0, stream>>>(ids, Etgt, Yh, Yl);
  p_wv<<<(32000*1024)/256, 256, 0, stream>>>(Wv, Wvb);

  k_gemm32<<<dim3(16, 128), 256, 0, stream>>>(vc, Wcat, batt, ep, vuu);

  k_loop<<<NBLK, 256, 0, stream>>>(Wgh, Wgl, Wuhh, Wuhl, Yh, Yl, ep, vuu,
                                   h, c, hhi, hlo, ohi, olo,
                                   ebuf, pa4, phB, gpart, comb, cnt);

  k_gemm16<<<dim3(NVB, 64), 256, 0, stream>>>(comb, Wvb, bv, pm, ps, gl, ids);
  k_reduce<<<64, 256, 0, stream>>>(pm, ps, gl, ids, out);
}

// Round 3
// 23472.066 us; speedup vs baseline: 1.8927x; 1.8927x over previous
//
#include <hip/hip_runtime.h>
#include <hip/hip_bf16.h>

#define TSTEPS 127
#define NBLK 256
#define NVB 250      // 32000/128
#define MROWS 8128   // 127*64

typedef __hip_bfloat16 bf16;
typedef unsigned short u16;
typedef unsigned int u32;
typedef unsigned long long u64;
typedef __attribute__((ext_vector_type(8))) short bf16x8;
typedef __attribute__((ext_vector_type(8))) unsigned short u16x8;
typedef __attribute__((ext_vector_type(4))) float f32x4;

__device__ __forceinline__ float us2f(u16 u){ union{float f;u32 i;}v; v.i=(u32)u<<16; return v.f; }
__device__ __forceinline__ u16 f2us(float f){ __hip_bfloat16 h=__float2bfloat16(f); u16 r; __builtin_memcpy(&r,&h,2); return r; }
__device__ __forceinline__ void split2(float x, u16& hi, u16& lo){
  u16 h = f2us(x); lo = f2us(x - us2f(h)); hi = h;
}

// ---- agent-scope (L2-bypassing) relaxed atomics ----
__device__ __forceinline__ u64 ldg64(const u64* p){
  return __hip_atomic_load((u64*)p, __ATOMIC_RELAXED, __HIP_MEMORY_SCOPE_AGENT);
}
__device__ __forceinline__ float ldgf(const float* p){
  return __hip_atomic_load((float*)p, __ATOMIC_RELAXED, __HIP_MEMORY_SCOPE_AGENT);
}
__device__ __forceinline__ void stg64(u64* p, u64 v){
  __hip_atomic_store(p, v, __ATOMIC_RELAXED, __HIP_MEMORY_SCOPE_AGENT);
}
__device__ __forceinline__ void stgf(float* p, float v){
  __hip_atomic_store(p, v, __ATOMIC_RELAXED, __HIP_MEMORY_SCOPE_AGENT);
}
__device__ __forceinline__ bf16x8 mk8(u64 a, u64 b){
  union { u64 q[2]; bf16x8 v; } u; u.q[0]=a; u.q[1]=b; return u.v;
}

// fence-free grid barrier: waitcnt drains sc-stores to coherence point; relaxed add/spin
__device__ __forceinline__ void gbar(u32* cnt, int id){
  asm volatile("s_waitcnt vmcnt(0) lgkmcnt(0)" ::: "memory");
  __syncthreads();
  if (threadIdx.x == 0){
    __hip_atomic_fetch_add(&cnt[id], 1u, __ATOMIC_RELAXED, __HIP_MEMORY_SCOPE_AGENT);
    while (__hip_atomic_load(&cnt[id], __ATOMIC_RELAXED, __HIP_MEMORY_SCOPE_AGENT) < (u32)NBLK)
      __builtin_amdgcn_s_sleep(2);
  }
  __syncthreads();
}

// ---------------- prep kernels ----------------
__global__ void p_wcat(const float* __restrict__ Watt, const float* __restrict__ Wu,
                       float* __restrict__ Wcat){
  int idx = blockIdx.x*256 + threadIdx.x;      // 2048*2048
  int n = idx >> 11, k = idx & 2047;
  Wcat[idx] = (n < 1024) ? Watt[idx] : Wu[(size_t)(n-1024)*3072 + k];
}

// Wg' rows reordered: row' = jj*4 + g  (j = g*1024 + jj); cols k: k<1536 Wih, else Whh
__global__ void p_wg(const float* __restrict__ Wih, const float* __restrict__ Whh,
                     u16* __restrict__ Wgh, u16* __restrict__ Wgl){
  int k = blockIdx.x*256 + threadIdx.x;        // 2560
  int rp = blockIdx.y;                         // 4096 (row')
  int jj = rp >> 2, g = rp & 3;
  int j = g*1024 + jj;
  float v = (k < 1536) ? Wih[(size_t)j*1536 + k] : Whh[(size_t)j*1024 + (k-1536)];
  u16 hi, lo; split2(v, hi, lo);
  Wgh[(size_t)rp*2560 + k] = hi; Wgl[(size_t)rp*2560 + k] = lo;
}

__global__ void p_wuh(const float* __restrict__ Wu, u16* __restrict__ Wh, u16* __restrict__ Wl){
  int k = blockIdx.x*256 + threadIdx.x;        // 1024
  int j = blockIdx.y;                          // 1024
  float v = Wu[(size_t)j*3072 + 2048 + k];
  u16 hi, lo; split2(v, hi, lo);
  Wh[(size_t)j*1024 + k] = hi; Wl[(size_t)j*1024 + k] = lo;
}

__global__ void p_y(const int* __restrict__ ids, const float* __restrict__ Etgt,
                    u16* __restrict__ Yh, u16* __restrict__ Yl){
  int e0 = blockIdx.x*256 + threadIdx.x;       // 512
  int row = blockIdx.y;                        // 8128
  int id = ids[row];
  float v = Etgt[(size_t)id*512 + e0];
  u16 hi, lo; split2(v, hi, lo);
  Yh[(size_t)row*512 + e0] = hi; Yl[(size_t)row*512 + e0] = lo;
}

__global__ void p_wv(const float* __restrict__ Wv, u16* __restrict__ Wvb){
  size_t idx = (size_t)blockIdx.x*256 + threadIdx.x;  // 32000*1024
  Wvb[idx] = f2us(Wv[idx]);
}

__global__ void p_init(const float* __restrict__ h0, const float* __restrict__ c0,
                       float* __restrict__ hf32, u16* __restrict__ hhi, u16* __restrict__ hlo,
                       u16* __restrict__ ohi, u16* __restrict__ olo,
                       float* __restrict__ cbuf, u32* __restrict__ cnt){
  int idx = blockIdx.x*256 + threadIdx.x;
  if (idx < 65536){
    float hv = h0[idx];
    hf32[idx] = hv;                 // buffer 0
    u16 a, b; split2(hv, a, b); hhi[idx] = a; hlo[idx] = b;
    cbuf[idx] = c0[idx];
    ohi[idx] = 0; olo[idx] = 0;
  } else if (idx < 65536 + 8704){
    cnt[idx - 65536] = 0;
  }
}

// ---------------- enc_proj + Vu GEMM (fp32 in, bf16 out): M=16384 N=2048 K=2048 ----
union SharedU {
  struct { u16 a[128*72]; u16 b[128*72]; } st;
  float cc[128*128];
};

__global__ __launch_bounds__(256) void k_gemm32(
    const float* __restrict__ A, const float* __restrict__ Bm,
    const float* __restrict__ bias, u16* __restrict__ ep, u16* __restrict__ vu)
{
  __shared__ SharedU sm;
  const int tid = threadIdx.x;
  const int lane = tid & 63, w = tid >> 6;
  const int wm = w >> 1, wn = w & 1;
  const int n0 = blockIdx.x * 128, m0 = blockIdx.y * 128;
  f32x4 acc[4][4];
#pragma unroll
  for (int i=0;i<4;i++)
#pragma unroll
    for (int j=0;j<4;j++) acc[i][j] = (f32x4)(0.f);

  for (int k0 = 0; k0 < 2048; k0 += 64) {
    __syncthreads();
#pragma unroll
    for (int i=0;i<8;i++){
      int idx = tid + i*256;
      int r = idx >> 4, c4 = idx & 15;
      float4 va = *(const float4*)(&A[(size_t)(m0+r)*2048 + k0 + c4*4]);
      ushort4 sa; sa.x=f2us(va.x); sa.y=f2us(va.y); sa.z=f2us(va.z); sa.w=f2us(va.w);
      *(ushort4*)(&sm.st.a[r*72 + c4*4]) = sa;
      float4 vb = *(const float4*)(&Bm[(size_t)(n0+r)*2048 + k0 + c4*4]);
      ushort4 sb; sb.x=f2us(vb.x); sb.y=f2us(vb.y); sb.z=f2us(vb.z); sb.w=f2us(vb.w);
      *(ushort4*)(&sm.st.b[r*72 + c4*4]) = sb;
    }
    __syncthreads();
#pragma unroll
    for (int kk = 0; kk < 64; kk += 32) {
      bf16x8 af[4], bfr[4];
      int krow = kk + ((lane >> 4) << 3);
#pragma unroll
      for (int m4=0;m4<4;m4++)
        af[m4] = *(const bf16x8*)(&sm.st.a[(wm*64 + m4*16 + (lane & 15))*72 + krow]);
#pragma unroll
      for (int n4=0;n4<4;n4++)
        bfr[n4] = *(const bf16x8*)(&sm.st.b[(wn*64 + n4*16 + (lane & 15))*72 + krow]);
#pragma unroll
      for (int m4=0;m4<4;m4++)
#pragma unroll
        for (int n4=0;n4<4;n4++)
          acc[m4][n4] = __builtin_amdgcn_mfma_f32_16x16x32_bf16(af[m4], bfr[n4], acc[m4][n4], 0,0,0);
    }
  }
  __syncthreads();
#pragma unroll
  for (int m4=0;m4<4;m4++)
#pragma unroll
    for (int n4=0;n4<4;n4++)
#pragma unroll
      for (int i=0;i<4;i++){
        int row = wm*64 + m4*16 + ((lane>>4)<<2) + i;
        int col = wn*64 + n4*16 + (lane&15);
        sm.cc[row*128 + col] = acc[m4][n4][i];
      }
  __syncthreads();
  for (int idx = tid; idx < 128*128; idx += 256) {
    int row = idx >> 7, col = idx & 127;
    int gm = m0 + row, gn = n0 + col;
    float vv = sm.cc[idx];
    if (gn < 1024) { vv += bias[gn]; ep[(size_t)gm*1024 + gn] = f2us(vv); }
    else           { vu[(size_t)gm*1024 + (gn-1024)] = f2us(vv); }
  }
}

// ---------------- persistent recurrence kernel ----------------
__global__ __launch_bounds__(256, 1) void k_loop(
    const u16* __restrict__ Wgh, const u16* __restrict__ Wgl,
    const u16* __restrict__ Wuhh, const u16* __restrict__ Wuhl,
    const u16* __restrict__ Yh, const u16* __restrict__ Yl,
    const u16* __restrict__ ep, const u16* __restrict__ vuu,
    float* __restrict__ hf32, u16* __restrict__ hhi, u16* __restrict__ hlo,
    u16* __restrict__ ohi, u16* __restrict__ olo,
    float* __restrict__ cbuf, float* __restrict__ gpart,
    float* __restrict__ ebuf, float* __restrict__ phB,
    u16* __restrict__ comb, u32* __restrict__ cnt)
{
  __shared__ float al[256];
  __shared__ float pared[4][256];
  __shared__ float red[8];

  const int tid = threadIdx.x, blk = blockIdx.x;
  const int lane = tid & 63, w = tid >> 6;
  const int l15 = lane & 15;
  const int q2 = (lane >> 4) * 2;        // u64 offset of fragment
  const int q8 = (lane >> 4) * 8;        // u16 offset of fragment
  u32* gflg = cnt + 512;

  for (int t = 0; t < TSTEPS; ++t) {
    const int p = t & 1;
    const u16* hhiP = hhi + p*65536;      const u16* hloP = hlo + p*65536;
    u16* hhiN = hhi + (p^1)*65536;        u16* hloN = hlo + (p^1)*65536;
    float* hfN = hf32 + (p^1)*65536;

    // ======== P1: gates reg-GEMM (K-split 4) + fused LSTM merge ========
    {
      const int bn = blk & 63, ks = blk >> 6;
      f32x4 acc[4];
#pragma unroll
      for (int i=0;i<4;i++) acc[i] = (f32x4)(0.f);
      const int jrow = bn*64 + w*16 + l15;           // row' of Wg' = output col
      const u16* bHp = Wgh + (size_t)jrow * 2560;
      const u16* bLp = Wgl + (size_t)jrow * 2560;
      for (int kt = 0; kt < 20; ++kt){
        const int kg = ks*640 + kt*32;
        const u64 *sH, *sL; int rst, kloc;
        if (kg < 1024){ sH=(const u64*)ohi; sL=(const u64*)olo; rst=256; kloc=kg; }
        else if (kg < 1536){
          sH=(const u64*)Yh + (size_t)(t*64)*128; sL=(const u64*)Yl + (size_t)(t*64)*128;
          rst=128; kloc=kg-1024;
        } else { sH=(const u64*)hhiP; sL=(const u64*)hloP; rst=256; kloc=kg-1536; }
        const int kq = (kloc >> 2) + q2;
        bf16x8 bh = *(const bf16x8*)(bHp + kg + q8);
        bf16x8 bl = *(const bf16x8*)(bLp + kg + q8);
        bf16x8 ah[4], av[4];
#pragma unroll
        for (int m=0;m<4;m++){
          int off = (m*16 + l15)*rst + kq;
          ah[m] = mk8(ldg64(sH+off), ldg64(sH+off+1));
          av[m] = mk8(ldg64(sL+off), ldg64(sL+off+1));
        }
#pragma unroll
        for (int m=0;m<4;m++) acc[m] = __builtin_amdgcn_mfma_f32_16x16x32_bf16(ah[m], bh, acc[m], 0,0,0);
#pragma unroll
        for (int m=0;m<4;m++) acc[m] = __builtin_amdgcn_mfma_f32_16x16x32_bf16(av[m], bh, acc[m], 0,0,0);
#pragma unroll
        for (int m=0;m<4;m++) acc[m] = __builtin_amdgcn_mfma_f32_16x16x32_bf16(ah[m], bl, acc[m], 0,0,0);
      }
      float* gp = gpart + (size_t)ks*64*4096;
      const int col = bn*64 + w*16 + l15;
#pragma unroll
      for (int m=0;m<4;m++)
#pragma unroll
        for (int i=0;i<4;i++){
          int b = m*16 + ((lane>>4)<<2) + i;
          stgf(gp + (size_t)b*4096 + col, acc[m][i]);
        }
      // producer flag
      asm volatile("s_waitcnt vmcnt(0)" ::: "memory");
      __syncthreads();
      if (tid == 0)
        __hip_atomic_fetch_add(&gflg[t*64+bn], 1u, __ATOMIC_RELAXED, __HIP_MEMORY_SCOPE_AGENT);
      if (ks == 0){
        if (tid == 0){
          while (__hip_atomic_load(&gflg[t*64+bn], __ATOMIC_RELAXED, __HIP_MEMORY_SCOPE_AGENT) < 4u)
            __builtin_amdgcn_s_sleep(1);
        }
        __syncthreads();
        // LSTM merge: thread = (b, q4), 4 consecutive jj
        const int b = tid >> 2, q4 = tid & 3;
        const int jjb = bn*16 + q4*4;
        float gv[16];
#pragma unroll
        for (int kss=0;kss<4;kss++){
          const u64* src = (const u64*)(gpart + ((size_t)(kss*64 + b))*4096 + jjb*4);
#pragma unroll
          for (int i2=0;i2<8;i2++){
            union{u64 q; float f[2];} uu; uu.q = ldg64(src + i2);
            if (kss==0){ gv[i2*2] = uu.f[0]; gv[i2*2+1] = uu.f[1]; }
            else       { gv[i2*2]+= uu.f[0]; gv[i2*2+1]+= uu.f[1]; }
          }
        }
        float4 cv = *(const float4*)(cbuf + (size_t)b*1024 + jjb);
        float hnew[4];
        float* cp = &cv.x;
#pragma unroll
        for (int jx=0;jx<4;jx++){
          float gi = gv[jx*4+0], gf = gv[jx*4+1], gg = gv[jx*4+2], go = gv[jx*4+3];
          gi = 1.f/(1.f+expf(-gi));
          gf = 1.f/(1.f+expf(-gf));
          gg = tanhf(gg);
          go = 1.f/(1.f+expf(-go));
          float cn = gf*cp[jx] + gi*gg;
          cp[jx] = cn;
          hnew[jx] = go*tanhf(cn);
        }
        *(float4*)(cbuf + (size_t)b*1024 + jjb) = cv;
        union{u64 q; float f[2];} pp;
        pp.f[0]=hnew[0]; pp.f[1]=hnew[1];
        stg64((u64*)(hfN + (size_t)b*1024 + jjb), pp.q);
        pp.f[0]=hnew[2]; pp.f[1]=hnew[3];
        stg64((u64*)(hfN + (size_t)b*1024 + jjb + 2), pp.q);
        union{u64 q; u16 s[4];} uh, ul;
#pragma unroll
        for (int jx=0;jx<4;jx++){ u16 a2,b2; split2(hnew[jx], a2, b2); uh.s[jx]=a2; ul.s[jx]=b2; }
        stg64((u64*)(hhiN + (size_t)b*1024 + jjb), uh.q);
        stg64((u64*)(hloN + (size_t)b*1024 + jjb), ul.q);
      }
    }
    gbar(cnt, t*3 + 0);

    // ======== P2: ph GEMM (blocks 0..15) + e_t (blocks 16..255) ========
    if (blk < 16){
      f32x4 acc[4];
#pragma unroll
      for (int i=0;i<4;i++) acc[i] = (f32x4)(0.f);
      const int jrow = blk*64 + w*16 + l15;
      const u16* bHp = Wuhh + (size_t)jrow*1024;
      const u16* bLp = Wuhl + (size_t)jrow*1024;
      const u64* sH = (const u64*)hhiN;
      const u64* sL = (const u64*)hloN;
      for (int kt = 0; kt < 32; ++kt){
        const int kg = kt*32;
        const int kq = (kg >> 2) + q2;
        bf16x8 bh = *(const bf16x8*)(bHp + kg + q8);
        bf16x8 bl = *(const bf16x8*)(bLp + kg + q8);
        bf16x8 ah[4], av[4];
#pragma unroll
        for (int m=0;m<4;m++){
          int off = (m*16 + l15)*256 + kq;
          ah[m] = mk8(ldg64(sH+off), ldg64(sH+off+1));
          av[m] = mk8(ldg64(sL+off), ldg64(sL+off+1));
        }
#pragma unroll
        for (int m=0;m<4;m++) acc[m] = __builtin_amdgcn_mfma_f32_16x16x32_bf16(ah[m], bh, acc[m], 0,0,0);
#pragma unroll
        for (int m=0;m<4;m++) acc[m] = __builtin_amdgcn_mfma_f32_16x16x32_bf16(av[m], bh, acc[m], 0,0,0);
#pragma unroll
        for (int m=0;m<4;m++) acc[m] = __builtin_amdgcn_mfma_f32_16x16x32_bf16(ah[m], bl, acc[m], 0,0,0);
      }
#pragma unroll
      for (int m=0;m<4;m++)
#pragma unroll
        for (int i=0;i<4;i++){
          int b = m*16 + ((lane>>4)<<2) + i;
          stgf(phB + (size_t)b*1024 + jrow, acc[m][i]);
        }
    } else {
      for (int u = blk - 16; u < 256; u += 240){
        const int b = u >> 2, sl = u & 3;
        float hr[16];
        const u64* hp = (const u64*)(hfN + (size_t)b*1024 + lane*16);
#pragma unroll
        for (int i=0;i<8;i++){
          union{u64 q; float f[2];} uu; uu.q = ldg64(hp + i);
          hr[i*2] = uu.f[0]; hr[i*2+1] = uu.f[1];
        }
        for (int rr = 0; rr < 16; ++rr){
          int s = sl*64 + w*16 + rr;
          const u16* row = ep + ((size_t)(b*256 + s))*1024 + lane*16;
          u16x8 v0 = *(const u16x8*)row;
          u16x8 v1 = *(const u16x8*)(row + 8);
          float a = 0.f;
#pragma unroll
          for (int j=0;j<8;j++) a += us2f(v0[j]) * hr[j];
#pragma unroll
          for (int j=0;j<8;j++) a += us2f(v1[j]) * hr[8+j];
#pragma unroll
          for (int off=32; off; off>>=1) a += __shfl_xor(a, off);
          if (lane == 0) stgf(ebuf + b*256 + s, a);
        }
      }
    }
    gbar(cnt, t*3 + 1);

    // ======== P3: softmax + pa + o_t (block = (b, j-quarter)) ========
    {
      const int b = blk >> 2, jq = blk & 3;
      float x = ldgf(ebuf + b*256 + tid);
      float m_ = x;
#pragma unroll
      for (int off=32; off; off>>=1) m_ = fmaxf(m_, __shfl_xor(m_, off));
      if (lane == 0) red[w] = m_;
      __syncthreads();
      m_ = fmaxf(fmaxf(red[0],red[1]), fmaxf(red[2],red[3]));
      float pv = expf(x - m_);
      float sv = pv;
#pragma unroll
      for (int off=32; off; off>>=1) sv += __shfl_xor(sv, off);
      if (lane == 0) red[4+w] = sv;
      __syncthreads();
      float tot = red[4]+red[5]+red[6]+red[7];
      al[tid] = pv / tot;
      __syncthreads();
      float a0=0.f, a1=0.f, a2=0.f, a3=0.f;
      const u16* vb = vuu + ((size_t)(b*256) + w*64)*1024 + jq*256 + lane*4;
      for (int s2=0; s2<64; s2++){
        float aa = al[w*64 + s2];
        ushort4 v = *(const ushort4*)(vb + (size_t)s2*1024);
        a0 += aa*us2f(v.x); a1 += aa*us2f(v.y); a2 += aa*us2f(v.z); a3 += aa*us2f(v.w);
      }
      float4 o4; o4.x=a0; o4.y=a1; o4.z=a2; o4.w=a3;
      *(float4*)(&pared[w][lane*4]) = o4;
      __syncthreads();
      if (tid < 64){
        const int col = tid*4;
        u16 his[4], los[4];
#pragma unroll
        for (int i=0;i<4;i++){
          float pa = pared[0][col+i] + pared[1][col+i] + pared[2][col+i] + pared[3][col+i];
          pa += ldgf(phB + (size_t)b*1024 + jq*256 + col + i);
          float o = tanhf(pa);
          split2(o, his[i], los[i]);
        }
        union{u64 q; u16 s[4];} uh, ul;
#pragma unroll
        for (int i=0;i<4;i++){ uh.s[i]=his[i]; ul.s[i]=los[i]; }
        stg64((u64*)(ohi + (size_t)b*1024 + jq*256 + col), uh.q);
        stg64((u64*)(olo + (size_t)b*1024 + jq*256 + col), ul.q);
        ushort4 cw; cw.x=his[0]; cw.y=his[1]; cw.z=his[2]; cw.w=his[3];
        *(ushort4*)(comb + (size_t)(t*64 + b)*1024 + jq*256 + col) = cw;   // plain store
      }
    }
    gbar(cnt, t*3 + 2);
  }
}

// ---------------- vocab GEMM (bf16 in) + fused softmax partials ----------------
__global__ __launch_bounds__(256) void k_gemm16(
    const u16* __restrict__ A, const u16* __restrict__ Bm,
    const float* __restrict__ bias,
    float* __restrict__ pm, float* __restrict__ ps,
    float* __restrict__ gl, const int* __restrict__ ids)
{
  __shared__ SharedU sm;
  const int tid = threadIdx.x;
  const int lane = tid & 63, w = tid >> 6;
  const int wm = w >> 1, wn = w & 1;
  const int n0 = blockIdx.x * 128, m0 = blockIdx.y * 128;
  f32x4 acc[4][4];
#pragma unroll
  for (int i=0;i<4;i++)
#pragma unroll
    for (int j=0;j<4;j++) acc[i][j] = (f32x4)(0.f);

  for (int k0 = 0; k0 < 1024; k0 += 64) {
    __syncthreads();
#pragma unroll
    for (int i=0;i<8;i++){
      int idx = i*256 + tid;
      int half = idx >> 10, id2 = idx & 1023;
      int r = id2 >> 3, c8 = (id2 & 7)*8;
      if (half == 0){
        int gm = m0 + r;
        u16x8 v = {0,0,0,0,0,0,0,0};
        if (gm < MROWS) v = *(const u16x8*)(A + (size_t)gm*1024 + k0 + c8);
        *(u16x8*)(&sm.st.a[r*72 + c8]) = v;
      } else {
        u16x8 v = *(const u16x8*)(Bm + (size_t)(n0 + r)*1024 + k0 + c8);
        *(u16x8*)(&sm.st.b[r*72 + c8]) = v;
      }
    }
    __syncthreads();
#pragma unroll
    for (int kk = 0; kk < 64; kk += 32) {
      bf16x8 af[4], bfr[4];
      int krow = kk + ((lane >> 4) << 3);
#pragma unroll
      for (int m4=0;m4<4;m4++)
        af[m4] = *(const bf16x8*)(&sm.st.a[(wm*64 + m4*16 + (lane & 15))*72 + krow]);
#pragma unroll
      for (int n4=0;n4<4;n4++)
        bfr[n4] = *(const bf16x8*)(&sm.st.b[(wn*64 + n4*16 + (lane & 15))*72 + krow]);
#pragma unroll
      for (int m4=0;m4<4;m4++)
#pragma unroll
        for (int n4=0;n4<4;n4++)
          acc[m4][n4] = __builtin_amdgcn_mfma_f32_16x16x32_bf16(af[m4], bfr[n4], acc[m4][n4], 0,0,0);
    }
  }
  __syncthreads();
#pragma unroll
  for (int m4=0;m4<4;m4++)
#pragma unroll
    for (int n4=0;n4<4;n4++)
#pragma unroll
      for (int i=0;i<4;i++){
        int row = wm*64 + m4*16 + ((lane>>4)<<2) + i;
        int col = wn*64 + n4*16 + (lane&15);
        sm.cc[row*128 + col] = acc[m4][n4][i];
      }
  __syncthreads();

  if (tid < 128) {
    int row = tid, gm = m0 + row;
    if (gm < MROWS) {
      float mx = -1e30f;
      for (int j=0;j<128;j++){
        int col = (row + j) & 127;
        float x = sm.cc[row*128+col] + bias[n0+col];
        mx = fmaxf(mx, x);
      }
      float sum = 0.f;
      for (int j=0;j<128;j++){
        int col = (row + j) & 127;
        float x = sm.cc[row*128+col] + bias[n0+col];
        sum += expf(x - mx);
      }
      pm[(size_t)gm*NVB + blockIdx.x] = mx;
      ps[(size_t)gm*NVB + blockIdx.x] = sum;
      int g = ids[gm + 64];
      unsigned d = (unsigned)(g - n0);
      if (d < 128u) gl[gm] = sm.cc[row*128 + (int)d] + bias[g];
    }
  }
}

// ---------------- final reduce ----------------
__global__ void k_reduce(const float* __restrict__ pm, const float* __restrict__ ps,
                         const float* __restrict__ gl, const int* __restrict__ ids,
                         float* __restrict__ out)
{
  int b = blockIdx.x, tid = threadIdx.x;
  int lane = tid & 63, w = tid >> 6;
  __shared__ float wacc[4];
  float accum = 0.f;
  for (int t = w; t < TSTEPS; t += 4) {
    int r = t*64 + b;
    const float* pmr = pm + (size_t)r*NVB;
    const float* psr = ps + (size_t)r*NVB;
    float mx = -1e30f;
    for (int p2 = lane; p2 < NVB; p2 += 64) mx = fmaxf(mx, pmr[p2]);
#pragma unroll
    for (int off=32; off; off>>=1) mx = fmaxf(mx, __shfl_xor(mx, off));
    float sm = 0.f;
    for (int p2 = lane; p2 < NVB; p2 += 64) sm += psr[p2] * expf(pmr[p2] - mx);
#pragma unroll
    for (int off=32; off; off>>=1) sm += __shfl_xor(sm, off);
    if (lane == 0) {
      int g = ids[r + 64];
      if (g != 0) accum += gl[r] - (mx + logf(sm));
    }
  }
  if (lane == 0) wacc[w] = accum;
  __syncthreads();
  if (tid == 0) out[b] = wacc[0]+wacc[1]+wacc[2]+wacc[3];
}

// ---------------- host ----------------
extern "C" void kernel_launch(void* const* d_in, const int* in_sizes, int n_in,
                              void* d_out, int out_size, void* d_ws, size_t ws_size,
                              hipStream_t stream)
{
  const int*   ids  = (const int*)d_in[0];
  const float* vc   = (const float*)d_in[1];
  const float* h0   = (const float*)d_in[2];
  const float* c0   = (const float*)d_in[3];
  const float* Etgt = (const float*)d_in[4];
  const float* Watt = (const float*)d_in[5];
  const float* batt = (const float*)d_in[6];
  const float* Wih  = (const float*)d_in[7];
  const float* Whh  = (const float*)d_in[8];
  const float* Wu   = (const float*)d_in[9];
  const float* Wv   = (const float*)d_in[10];
  const float* bv   = (const float*)d_in[11];
  float* out = (float*)d_out;

  char* p = (char*)d_ws;
  auto alloc = [&](size_t bytes)->char* {
    char* r = p; p += (bytes + 255) & ~(size_t)255; return r;
  };
  u32* cnt   = (u32*)alloc(64*1024);                          // 512 barriers + 8128 flags
  u16* Yh    = (u16*)alloc((size_t)MROWS*512*2);
  u16* Yl    = (u16*)alloc((size_t)MROWS*512*2);
  u16* Wgh   = (u16*)alloc((size_t)4096*2560*2);
  u16* Wgl   = (u16*)alloc((size_t)4096*2560*2);
  u16* Wuhh  = (u16*)alloc((size_t)1024*1024*2);
  u16* Wuhl  = (u16*)alloc((size_t)1024*1024*2);
  float* Wcat= (float*)alloc((size_t)2048*2048*4);
  u16* ep    = (u16*)alloc((size_t)64*256*1024*2);
  u16* vuu   = (u16*)alloc((size_t)64*256*1024*2);
  u16* Wvb   = (u16*)alloc((size_t)32000*1024*2);
  u16* comb  = (u16*)alloc((size_t)MROWS*1024*2);
  float* hf32= (float*)alloc((size_t)2*65536*4);
  u16* hhi   = (u16*)alloc((size_t)2*65536*2);
  u16* hlo   = (u16*)alloc((size_t)2*65536*2);
  u16* ohi   = (u16*)alloc(65536*2);
  u16* olo   = (u16*)alloc(65536*2);
  float* cbuf= (float*)alloc(65536*4);
  float* gpart=(float*)alloc((size_t)4*64*4096*4);
  float* ebuf= (float*)alloc((size_t)64*256*4);
  float* phB = (float*)alloc((size_t)64*1024*4);
  float* pm  = (float*)alloc((size_t)MROWS*NVB*4);
  float* ps  = (float*)alloc((size_t)MROWS*NVB*4);
  float* gl  = (float*)alloc((size_t)MROWS*4);

  p_init<<<291, 256, 0, stream>>>(h0, c0, hf32, hhi, hlo, ohi, olo, cbuf, cnt);
  p_wcat<<<(2048*2048)/256, 256, 0, stream>>>(Watt, Wu, Wcat);
  p_wg<<<dim3(10, 4096), 256, 0, stream>>>(Wih, Whh, Wgh, Wgl);
  p_wuh<<<dim3(4, 1024), 256, 0, stream>>>(Wu, Wuhh, Wuhl);
  p_y<<<dim3(2, MROWS), 256, 0, stream>>>(ids, Etgt, Yh, Yl);
  p_wv<<<(32000*1024)/256, 256, 0, stream>>>(Wv, Wvb);

  k_gemm32<<<dim3(16, 128), 256, 0, stream>>>(vc, Wcat, batt, ep, vuu);

  k_loop<<<NBLK, 256, 0, stream>>>(Wgh, Wgl, Wuhh, Wuhl, Yh, Yl, ep, vuu,
                                   hf32, hhi, hlo, ohi, olo, cbuf, gpart,
                                   ebuf, phB, comb, cnt);

  k_gemm16<<<dim3(NVB, 64), 256, 0, stream>>>(comb, Wvb, bv, pm, ps, gl, ids);
  k_reduce<<<64, 256, 0, stream>>>(pm, ps, gl, ids, out);
}